// Round 16
// baseline (147.752 us; speedup 1.0000x reference)
//
#include <hip/hip_runtime.h>
#include <math.h>

typedef __bf16 bf16_t;
typedef __bf16 bf16x8 __attribute__((ext_vector_type(8)));
typedef float f32x4 __attribute__((ext_vector_type(4)));
typedef int i32x4 __attribute__((ext_vector_type(4)));
typedef int i32x2 __attribute__((ext_vector_type(2)));

#define SW_SCALE 0.03952847075f /* 1/sqrt(640) */

#define GLOAD_LDS16(g, l)                                                      \
  __builtin_amdgcn_global_load_lds(                                            \
      (const __attribute__((address_space(1))) void*)(g),                      \
      (__attribute__((address_space(3))) void*)(l), 16, 0, 0)

// ---------------------------------------------------------------------------
// Prep: bf16 stage-1 operands + plain i8 [v][f] W_out.
// ---------------------------------------------------------------------------
__global__ __launch_bounds__(256) void prep_kernel(
    const float* __restrict__ enc, const float* __restrict__ dec,
    const float* __restrict__ ot, const float* __restrict__ W_enc,
    const float* __restrict__ W_ot, const float* __restrict__ W_dec,
    const float* __restrict__ W_out, bf16_t* __restrict__ Acat,
    bf16_t* __restrict__ Dec, bf16_t* __restrict__ WcatT,
    bf16_t* __restrict__ WdecT, signed char* __restrict__ WoutT8) {
  __shared__ float T[32][33];
  const int tid = threadIdx.x;
  const int b = blockIdx.x;

  if (b < 900) {  // elementwise bf16x8 copies
    const int idx8 = (b * 256 + tid) * 8;
    const int N0 = 1600 * 1024;
    if (idx8 < N0) {
      const int r = idx8 >> 10, c = idx8 & 1023;
      const float* src = (c < 512) ? enc + (r << 9) + c : ot + (r << 9) + c - 512;
      f32x4 v0 = *(const f32x4*)src;
      f32x4 v1 = *(const f32x4*)(src + 4);
      bf16x8 o;
#pragma unroll
      for (int e = 0; e < 4; ++e) {
        o[e] = (bf16_t)v0[e];
        o[e + 4] = (bf16_t)v1[e];
      }
      *(bf16x8*)(Acat + idx8) = o;
    } else {
      const int j = idx8 - N0;
      if (j < 400 * 512) {
        f32x4 v0 = *(const f32x4*)(dec + j);
        f32x4 v1 = *(const f32x4*)(dec + j + 4);
        bf16x8 o;
#pragma unroll
        for (int e = 0; e < 4; ++e) {
          o[e] = (bf16_t)v0[e];
          o[e + 4] = (bf16_t)v1[e];
        }
        *(bf16x8*)(Dec + j) = o;
      }
    }
    return;
  }

  const int tx = tid & 31, ty = tid >> 5;
  if (b < 1540) {  // WcatT [f][k] <- [k][f]
    const int b2 = b - 900;
    const int kt = b2 / 20, ft = b2 - kt * 20;
    const int k0 = kt * 32, f0 = ft * 32;
#pragma unroll
    for (int j = 0; j < 4; ++j) {
      const int kk = k0 + ty + j * 8;
      T[ty + j * 8][tx] = (kk < 512) ? W_enc[kk * 640 + f0 + tx]
                                     : W_ot[(kk - 512) * 640 + f0 + tx];
    }
    __syncthreads();
#pragma unroll
    for (int j = 0; j < 4; ++j) {
      const int ff = f0 + ty + j * 8;
      WcatT[ff * 1024 + k0 + tx] = (bf16_t)T[tx][ty + j * 8];
    }
    return;
  }
  if (b < 1860) {  // WdecT [f][k] <- [k][f]
    const int b2 = b - 1540;
    const int kt = b2 / 20, ft = b2 - kt * 20;
    const int k0 = kt * 32, f0 = ft * 32;
#pragma unroll
    for (int j = 0; j < 4; ++j)
      T[ty + j * 8][tx] = W_dec[(k0 + ty + j * 8) * 640 + f0 + tx];
    __syncthreads();
#pragma unroll
    for (int j = 0; j < 4; ++j) {
      const int ff = f0 + ty + j * 8;
      WdecT[ff * 512 + k0 + tx] = (bf16_t)T[tx][ty + j * 8];
    }
    return;
  }
  {  // WoutT8 [v][f] i8 <- W_out [f][v], 32x32 tiles
    const int b2 = b - 1860;  // 0..639
    const int vt = b2 / 20, ft = b2 - vt * 20;
    const int v0 = vt * 32, f0 = ft * 32;
#pragma unroll
    for (int j = 0; j < 4; ++j)
      T[ty + j * 8][tx] = W_out[(f0 + ty + j * 8) * 1024 + v0 + tx];
    __syncthreads();
#pragma unroll
    for (int j = 0; j < 4; ++j) {
      const int vv = v0 + ty + j * 8;
      float w = T[tx][ty + j * 8] * (127.0f / SW_SCALE);
      w = fminf(fmaxf(w, -127.0f), 127.0f);
      WoutT8[(size_t)vv * 640 + f0 + tx] = (signed char)__float2int_rn(w);
    }
  }
}

// ---------------------------------------------------------------------------
// Stage 1 (R16): MERGED single dispatch for both tanh-GEMMs; barrier-free,
// wave-private LDS, prefetch DISTANCE 2 (3-slot ring, vmcnt(8) ledger).
//  blockIdx.y < 25 : ta = tanh(Acat@WcatT + b_enc + b_ot), M=1600, K=1024
//  blockIdx.y >= 25: tb = tanh(Dec @WdecT + b_dec),        M=400,  K=512
// ---------------------------------------------------------------------------
__global__ __launch_bounds__(256) void stage1_kernel(
    const bf16_t* __restrict__ Acat, const bf16_t* __restrict__ WcatT,
    const float* __restrict__ b_enc, const float* __restrict__ b_ot,
    float* __restrict__ ta, const bf16_t* __restrict__ Dec,
    const bf16_t* __restrict__ WdecT, const float* __restrict__ b_dec,
    float* __restrict__ tb) {
  __shared__ __align__(16) unsigned char L[3][16384];
  const int tid = threadIdx.x;
  const int wid = tid >> 6, l = tid & 63;
  const int wm = wid >> 1, wn = wid & 1;

  const bool big = (blockIdx.y < 25);
  const int M = big ? 1600 : 400;
  const int K = big ? 1024 : 512;
  const bf16_t* A = big ? Acat : Dec;
  const bf16_t* Bt = big ? WcatT : WdecT;
  const float* bias1 = big ? b_enc : b_dec;
  const float* bias2 = big ? b_ot : nullptr;
  float* out = big ? ta : tb;
  const int r0 = (big ? blockIdx.y : blockIdx.y - 25) * 64;
  const int n0 = blockIdx.x * 64;

  const int sperm = ((l & 3) ^ ((l >> 3) & 3)) * 8;
  int ra0 = r0 + wm * 32 + (l >> 2);
  if (ra0 > M - 1) ra0 = M - 1;
  int ra1 = r0 + wm * 32 + 16 + (l >> 2);
  if (ra1 > M - 1) ra1 = M - 1;
  const bf16_t* gA0 = A + (size_t)ra0 * K + sperm;
  const bf16_t* gA1 = A + (size_t)ra1 * K + sperm;
  const bf16_t* gB0 = Bt + (size_t)(n0 + wn * 32 + (l >> 2)) * K + sperm;
  const bf16_t* gB1 = gB0 + (size_t)16 * K;
  const int wb = wid * 4096;

  const int lr = l & 15, kg = l >> 4;
  const int swz = (kg ^ ((lr >> 1) & 3)) << 4;
  const int aO = wb + lr * 64 + swz;
  const int bO = wb + 2048 + lr * 64 + swz;

#define ST1_STAGE(t, s)                                                        \
  {                                                                            \
    GLOAD_LDS16(gA0 + (t) * 32, L[s] + wb);                                    \
    GLOAD_LDS16(gA1 + (t) * 32, L[s] + wb + 1024);                             \
    GLOAD_LDS16(gB0 + (t) * 32, L[s] + wb + 2048);                             \
    GLOAD_LDS16(gB1 + (t) * 32, L[s] + wb + 3072);                             \
  }

  f32x4 acc[2][2] = {};
  const int steps = K >> 5;  // 32 or 16
  ST1_STAGE(0, 0);
  ST1_STAGE(1, 1);
#pragma unroll 1
  for (int ks = 0; ks < steps; ++ks) {
    const int cur = ks % 3;
    if (ks < steps - 2) {
      ST1_STAGE(ks + 2, (ks + 2) % 3);
      __builtin_amdgcn_sched_barrier(0);
      asm volatile("s_waitcnt vmcnt(8)" ::: "memory");  // g(ks) landed
    } else if (ks == steps - 2) {
      asm volatile("s_waitcnt vmcnt(4)" ::: "memory");
    } else {
      asm volatile("s_waitcnt vmcnt(0)" ::: "memory");
    }
    __builtin_amdgcn_sched_barrier(0);
    bf16x8 af[2], bfr[2];
#pragma unroll
    for (int a = 0; a < 2; ++a)
      af[a] = *(const bf16x8*)(L[cur] + aO + a * 1024);
#pragma unroll
    for (int b = 0; b < 2; ++b)
      bfr[b] = *(const bf16x8*)(L[cur] + bO + b * 1024);
#pragma unroll
    for (int a = 0; a < 2; ++a)
#pragma unroll
      for (int b = 0; b < 2; ++b)
        acc[a][b] = __builtin_amdgcn_mfma_f32_16x16x32_bf16(af[a], bfr[b],
                                                            acc[a][b], 0, 0, 0);
  }
#undef ST1_STAGE

#pragma unroll
  for (int a = 0; a < 2; ++a)
#pragma unroll
    for (int b = 0; b < 2; ++b) {
      int col = n0 + wn * 32 + b * 16 + lr;
      float bv = bias1[col] + (bias2 ? bias2[col] : 0.0f);
#pragma unroll
      for (int j = 0; j < 4; ++j) {
        int rg = r0 + wm * 32 + a * 16 + kg * 4 + j;
        if (rg < M) out[(size_t)rg * 640 + col] = tanhf(acc[a][b][j] + bv);
      }
    }
}

// ---------------------------------------------------------------------------
// Materialize i8 joint A: A8[80128][656-pad] = q127(tanh(ta(+)tb)).
// ---------------------------------------------------------------------------
__global__ __launch_bounds__(256) void materialize8_kernel(
    const float* __restrict__ ta,   // [1600][640]
    const float* __restrict__ tb,   // [400][640]
    signed char* __restrict__ A8) { // [80128][656]
  const int idx = blockIdx.x * 256 + threadIdx.x;  // exactly 80000*80
  const int row = idx / 80;
  const int c8 = idx - row * 80;
  const int frow = row / 50;
  const int bidx = row / 10000;
  const int u = row - frow * 50;
  const float* tap = ta + (size_t)frow * 640 + c8 * 8;
  const float* tbp = tb + (size_t)(bidx * 50 + u) * 640 + c8 * 8;
  f32x4 xa0 = *(const f32x4*)tap, xa1 = *(const f32x4*)(tap + 4);
  f32x4 xb0 = *(const f32x4*)tbp, xb1 = *(const f32x4*)(tbp + 4);
  int q[8];
#pragma unroll
  for (int e = 0; e < 4; ++e) {
    float d0 = fmaxf(1.0f + xa0[e] * xb0[e], 1e-6f);
    q[e] = __float2int_rn((xa0[e] + xb0[e]) * __builtin_amdgcn_rcpf(d0) * 127.0f);
    float d1 = fmaxf(1.0f + xa1[e] * xb1[e], 1e-6f);
    q[e + 4] =
        __float2int_rn((xa1[e] + xb1[e]) * __builtin_amdgcn_rcpf(d1) * 127.0f);
  }
  i32x2 pk;
  pk[0] = (q[0] & 255) | ((q[1] & 255) << 8) | ((q[2] & 255) << 16) | (q[3] << 24);
  pk[1] = (q[4] & 255) | ((q[5] & 255) << 8) | ((q[6] & 255) << 16) | (q[7] << 24);
  *(i32x2*)(A8 + (size_t)row * 656 + c8 * 8) = pk;
}

// ---------------------------------------------------------------------------
// Stage 2 (R16): M-streaming joint GEMM (R15 schedule), FINER blocks.
//  Block = (col-strip of 128, M-range of 128 rows = 4 chunks of 32).
//  Grid 5120 (5000 active) ~= 2 blocks/CU with better tail balance; same
//  continuous per-chunk stores that produced R15's -48 us.
//  XCD map: wg=(orig&7)*640+(orig>>3); mg=wg>>3 (XCD x owns mg [80x,80x+80)),
//  strip=wg&7 -> the 8 strips of one mg adjacent on one XCD (A8 L2-shared).
//  625*128 = 80000 exactly.
// ---------------------------------------------------------------------------
__global__ __launch_bounds__(512, 4) void joint_gemm_kernel(
    const signed char* __restrict__ A8,  // [80128][656]
    const signed char* __restrict__ W8,  // [1024][640]
    const float* __restrict__ b_out,     // [1024]
    float* __restrict__ out) {           // [80000][1024]
  __shared__ __align__(16) signed char Al[2][21504];  // chunk dbuf
  __shared__ __align__(16) float Tr[8][32 * 20];      // per-wave transpose
  const int tid = threadIdx.x;
  const int w = tid >> 6, l = tid & 63;
  const int lr = l & 15, kg = l >> 4;

  const int orig = blockIdx.x;  // grid 5120
  const int mg = (orig & 7) * 80 + (orig >> 6);
  const int strip = (orig >> 3) & 7;
  if (mg >= 625) return;
  const int c0w = strip * 128 + w * 16;

  // ---- B: 10 frags in registers, loaded once ----
  i32x4 Bf[10];
  const signed char* gW = W8 + (size_t)(c0w + lr) * 640 + kg * 16;
#pragma unroll
  for (int t = 0; t < 10; ++t) Bf[t] = *(const i32x4*)(gW + t * 64);
  const float bv = b_out[c0w + lr];

  // ---- staging assignment: wave w issues insts [w*3, min(w*3+3,21)) ----
  const int i0 = w * 3;
  const int ni = (i0 < 21) ? ((i0 + 3 <= 21) ? 3 : 21 - i0) : 0;
  const size_t mbase = (size_t)mg * 128 * 656;

#define JSTAGE(c, buf)                                                         \
  {                                                                            \
    const signed char* s_ = A8 + mbase + (size_t)(c) * (32 * 656);             \
    for (int k_ = 0; k_ < ni; ++k_) {                                          \
      const int i_ = i0 + k_;                                                  \
      const int off_ = (i_ == 20) ? 19968 : i_ * 1024;                         \
      GLOAD_LDS16(s_ + off_ + l * 16, Al[buf] + off_);                         \
    }                                                                          \
  }

  // ---- prologue: stage chunk 0 ----
  JSTAGE(0, 0);

  const float cfac = SW_SCALE / (127.0f * 127.0f);
  float* trw = Tr[w];

#pragma unroll 1
  for (int c = 0; c < 4; ++c) {
    const int buf = c & 1;
    if (c < 3) JSTAGE(c + 1, buf ^ 1);
    __builtin_amdgcn_sched_barrier(0);
    // FIFO ledger: [B=10,bv=1,g0=3] at c=0; then [g(c)=3][st(c-1)=2][g(c+1)=3]
    if (c == 0) {
      asm volatile("s_waitcnt vmcnt(3)" ::: "memory");  // B + bv + g0 done
    } else if (c < 3) {
      asm volatile("s_waitcnt vmcnt(5)" ::: "memory");  // g(c) done
    } else {
      asm volatile("s_waitcnt vmcnt(2)" ::: "memory");  // g3 done
    }
    __builtin_amdgcn_sched_barrier(0);
    __builtin_amdgcn_s_barrier();  // all waves' parts of chunk c visible
    __builtin_amdgcn_sched_barrier(0);

    // ---- compute: 2 row-groups x 10 K-frags ----
    i32x4 acc0 = {}, acc1 = {};
#pragma unroll
    for (int t = 0; t < 10; ++t) {
      i32x4 a0 = *(const i32x4*)(Al[buf] + lr * 656 + t * 64 + kg * 16);
      i32x4 a1 = *(const i32x4*)(Al[buf] + (16 + lr) * 656 + t * 64 + kg * 16);
      acc0 = __builtin_amdgcn_mfma_i32_16x16x64_i8(a0, Bf[t], acc0, 0, 0, 0);
      acc1 = __builtin_amdgcn_mfma_i32_16x16x64_i8(a1, Bf[t], acc1, 0, 0, 0);
    }

    // ---- per-wave transpose (Tr private -> no cross-wave sync) ----
#pragma unroll
    for (int j = 0; j < 4; ++j) {
      trw[(kg * 4 + j) * 20 + lr] = (float)acc0[j] * cfac + bv;
      trw[(16 + kg * 4 + j) * 20 + lr] = (float)acc1[j] * cfac + bv;
    }
    asm volatile("s_waitcnt lgkmcnt(0)" ::: "memory");
    // ---- stores: 2 x nt dwordx4 per lane ----
    const int part = l & 3;
#pragma unroll
    for (int it = 0; it < 2; ++it) {
      const int row = it * 16 + (l >> 2);
      f32x4 v = *(const f32x4*)(trw + row * 20 + part * 4);
      const int grow = mg * 128 + c * 32 + row;
      __builtin_nontemporal_store(
          v, (f32x4*)(out + (size_t)grow * 1024 + c0w + part * 4));
    }
    __builtin_amdgcn_sched_barrier(0);
    __builtin_amdgcn_s_barrier();  // reads of chunk c done before reuse
  }
#undef JSTAGE
}

// ---------------------------------------------------------------------------
extern "C" void kernel_launch(void* const* d_in, const int* in_sizes, int n_in,
                              void* d_out, int out_size, void* d_ws,
                              size_t ws_size, hipStream_t stream) {
  const float* enc = (const float*)d_in[0];
  const float* dec = (const float*)d_in[1];
  const float* ot = (const float*)d_in[2];
  const float* W_enc = (const float*)d_in[3];
  const float* b_enc = (const float*)d_in[4];
  const float* W_ot = (const float*)d_in[5];
  const float* b_ot = (const float*)d_in[6];
  const float* W_dec = (const float*)d_in[7];
  const float* b_dec = (const float*)d_in[8];
  const float* W_out = (const float*)d_in[9];
  const float* b_out = (const float*)d_in[10];
  float* out = (float*)d_out;

  char* ws = (char*)d_ws;
  size_t off = 0;
  auto alloc = [&](size_t bytes) {
    void* p = ws + off;
    off += (bytes + 255) & ~(size_t)255;
    return p;
  };
  float* ta = (float*)alloc(1600 * 640 * 4);
  float* tb = (float*)alloc(400 * 640 * 4);
  bf16_t* Acat = (bf16_t*)alloc(1600 * 1024 * 2);
  bf16_t* Dec = (bf16_t*)alloc(400 * 512 * 2);
  bf16_t* WcatT = (bf16_t*)alloc(640 * 1024 * 2);
  bf16_t* WdecT = (bf16_t*)alloc(640 * 512 * 2);
  signed char* WoutT8 = (signed char*)alloc(1024 * 640);
  signed char* A8 = (signed char*)alloc((size_t)80128 * 656);

  prep_kernel<<<2500, 256, 0, stream>>>(enc, dec, ot, W_enc, W_ot, W_dec,
                                        W_out, Acat, Dec, WcatT, WdecT, WoutT8);
  // merged stage 1: y<25 -> ta (M=1600,K=1024); y>=25 -> tb (M=400,K=512)
  stage1_kernel<<<dim3(10, 32), 256, 0, stream>>>(Acat, WcatT, b_enc, b_ot, ta,
                                                  Dec, WdecT, b_dec, tb);
  materialize8_kernel<<<25000, 256, 0, stream>>>(ta, tb, A8);
  // joint: M-streaming, 128-row ranges (4 chunks), continuous stores
  joint_gemm_kernel<<<5120, 512, 0, stream>>>(A8, WoutT8, b_out, out);
}

// Round 17
// 138.189 us; speedup vs baseline: 1.0692x; 1.0692x over previous
//
#include <hip/hip_runtime.h>
#include <math.h>

typedef __bf16 bf16_t;
typedef __bf16 bf16x8 __attribute__((ext_vector_type(8)));
typedef float f32x4 __attribute__((ext_vector_type(4)));
typedef int i32x4 __attribute__((ext_vector_type(4)));
typedef int i32x2 __attribute__((ext_vector_type(2)));

#define SW_SCALE 0.03952847075f /* 1/sqrt(640) */

#define GLOAD_LDS16(g, l)                                                      \
  __builtin_amdgcn_global_load_lds(                                            \
      (const __attribute__((address_space(1))) void*)(g),                      \
      (__attribute__((address_space(3))) void*)(l), 16, 0, 0)

// ---------------------------------------------------------------------------
// Prep: bf16 stage-1 operands + plain i8 [v][f] W_out.
// ---------------------------------------------------------------------------
__global__ __launch_bounds__(256) void prep_kernel(
    const float* __restrict__ enc, const float* __restrict__ dec,
    const float* __restrict__ ot, const float* __restrict__ W_enc,
    const float* __restrict__ W_ot, const float* __restrict__ W_dec,
    const float* __restrict__ W_out, bf16_t* __restrict__ Acat,
    bf16_t* __restrict__ Dec, bf16_t* __restrict__ WcatT,
    bf16_t* __restrict__ WdecT, signed char* __restrict__ WoutT8) {
  __shared__ float T[32][33];
  const int tid = threadIdx.x;
  const int b = blockIdx.x;

  if (b < 900) {  // elementwise bf16x8 copies
    const int idx8 = (b * 256 + tid) * 8;
    const int N0 = 1600 * 1024;
    if (idx8 < N0) {
      const int r = idx8 >> 10, c = idx8 & 1023;
      const float* src = (c < 512) ? enc + (r << 9) + c : ot + (r << 9) + c - 512;
      f32x4 v0 = *(const f32x4*)src;
      f32x4 v1 = *(const f32x4*)(src + 4);
      bf16x8 o;
#pragma unroll
      for (int e = 0; e < 4; ++e) {
        o[e] = (bf16_t)v0[e];
        o[e + 4] = (bf16_t)v1[e];
      }
      *(bf16x8*)(Acat + idx8) = o;
    } else {
      const int j = idx8 - N0;
      if (j < 400 * 512) {
        f32x4 v0 = *(const f32x4*)(dec + j);
        f32x4 v1 = *(const f32x4*)(dec + j + 4);
        bf16x8 o;
#pragma unroll
        for (int e = 0; e < 4; ++e) {
          o[e] = (bf16_t)v0[e];
          o[e + 4] = (bf16_t)v1[e];
        }
        *(bf16x8*)(Dec + j) = o;
      }
    }
    return;
  }

  const int tx = tid & 31, ty = tid >> 5;
  if (b < 1540) {  // WcatT [f][k] <- [k][f]
    const int b2 = b - 900;
    const int kt = b2 / 20, ft = b2 - kt * 20;
    const int k0 = kt * 32, f0 = ft * 32;
#pragma unroll
    for (int j = 0; j < 4; ++j) {
      const int kk = k0 + ty + j * 8;
      T[ty + j * 8][tx] = (kk < 512) ? W_enc[kk * 640 + f0 + tx]
                                     : W_ot[(kk - 512) * 640 + f0 + tx];
    }
    __syncthreads();
#pragma unroll
    for (int j = 0; j < 4; ++j) {
      const int ff = f0 + ty + j * 8;
      WcatT[ff * 1024 + k0 + tx] = (bf16_t)T[tx][ty + j * 8];
    }
    return;
  }
  if (b < 1860) {  // WdecT [f][k] <- [k][f]
    const int b2 = b - 1540;
    const int kt = b2 / 20, ft = b2 - kt * 20;
    const int k0 = kt * 32, f0 = ft * 32;
#pragma unroll
    for (int j = 0; j < 4; ++j)
      T[ty + j * 8][tx] = W_dec[(k0 + ty + j * 8) * 640 + f0 + tx];
    __syncthreads();
#pragma unroll
    for (int j = 0; j < 4; ++j) {
      const int ff = f0 + ty + j * 8;
      WdecT[ff * 512 + k0 + tx] = (bf16_t)T[tx][ty + j * 8];
    }
    return;
  }
  {  // WoutT8 [v][f] i8 <- W_out [f][v], 32x32 tiles
    const int b2 = b - 1860;  // 0..639
    const int vt = b2 / 20, ft = b2 - vt * 20;
    const int v0 = vt * 32, f0 = ft * 32;
#pragma unroll
    for (int j = 0; j < 4; ++j)
      T[ty + j * 8][tx] = W_out[(f0 + ty + j * 8) * 1024 + v0 + tx];
    __syncthreads();
#pragma unroll
    for (int j = 0; j < 4; ++j) {
      const int vv = v0 + ty + j * 8;
      float w = T[tx][ty + j * 8] * (127.0f / SW_SCALE);
      w = fminf(fmaxf(w, -127.0f), 127.0f);
      WoutT8[(size_t)vv * 640 + f0 + tx] = (signed char)__float2int_rn(w);
    }
  }
}

// ---------------------------------------------------------------------------
// Stage 1 (merged, dist-2): both tanh-GEMMs in one dispatch; barrier-free,
// wave-private LDS, 3-slot ring, vmcnt(8) ledger.
//  blockIdx.y < 25 : ta = tanh(Acat@WcatT + b_enc + b_ot), M=1600, K=1024
//  blockIdx.y >= 25: tb = tanh(Dec @WdecT + b_dec),        M=400,  K=512
// ---------------------------------------------------------------------------
__global__ __launch_bounds__(256) void stage1_kernel(
    const bf16_t* __restrict__ Acat, const bf16_t* __restrict__ WcatT,
    const float* __restrict__ b_enc, const float* __restrict__ b_ot,
    float* __restrict__ ta, const bf16_t* __restrict__ Dec,
    const bf16_t* __restrict__ WdecT, const float* __restrict__ b_dec,
    float* __restrict__ tb) {
  __shared__ __align__(16) unsigned char L[3][16384];
  const int tid = threadIdx.x;
  const int wid = tid >> 6, l = tid & 63;
  const int wm = wid >> 1, wn = wid & 1;

  const bool big = (blockIdx.y < 25);
  const int M = big ? 1600 : 400;
  const int K = big ? 1024 : 512;
  const bf16_t* A = big ? Acat : Dec;
  const bf16_t* Bt = big ? WcatT : WdecT;
  const float* bias1 = big ? b_enc : b_dec;
  const float* bias2 = big ? b_ot : nullptr;
  float* out = big ? ta : tb;
  const int r0 = (big ? blockIdx.y : blockIdx.y - 25) * 64;
  const int n0 = blockIdx.x * 64;

  const int sperm = ((l & 3) ^ ((l >> 3) & 3)) * 8;
  int ra0 = r0 + wm * 32 + (l >> 2);
  if (ra0 > M - 1) ra0 = M - 1;
  int ra1 = r0 + wm * 32 + 16 + (l >> 2);
  if (ra1 > M - 1) ra1 = M - 1;
  const bf16_t* gA0 = A + (size_t)ra0 * K + sperm;
  const bf16_t* gA1 = A + (size_t)ra1 * K + sperm;
  const bf16_t* gB0 = Bt + (size_t)(n0 + wn * 32 + (l >> 2)) * K + sperm;
  const bf16_t* gB1 = gB0 + (size_t)16 * K;
  const int wb = wid * 4096;

  const int lr = l & 15, kg = l >> 4;
  const int swz = (kg ^ ((lr >> 1) & 3)) << 4;
  const int aO = wb + lr * 64 + swz;
  const int bO = wb + 2048 + lr * 64 + swz;

#define ST1_STAGE(t, s)                                                        \
  {                                                                            \
    GLOAD_LDS16(gA0 + (t) * 32, L[s] + wb);                                    \
    GLOAD_LDS16(gA1 + (t) * 32, L[s] + wb + 1024);                             \
    GLOAD_LDS16(gB0 + (t) * 32, L[s] + wb + 2048);                             \
    GLOAD_LDS16(gB1 + (t) * 32, L[s] + wb + 3072);                             \
  }

  f32x4 acc[2][2] = {};
  const int steps = K >> 5;  // 32 or 16
  ST1_STAGE(0, 0);
  ST1_STAGE(1, 1);
#pragma unroll 1
  for (int ks = 0; ks < steps; ++ks) {
    const int cur = ks % 3;
    if (ks < steps - 2) {
      ST1_STAGE(ks + 2, (ks + 2) % 3);
      __builtin_amdgcn_sched_barrier(0);
      asm volatile("s_waitcnt vmcnt(8)" ::: "memory");  // g(ks) landed
    } else if (ks == steps - 2) {
      asm volatile("s_waitcnt vmcnt(4)" ::: "memory");
    } else {
      asm volatile("s_waitcnt vmcnt(0)" ::: "memory");
    }
    __builtin_amdgcn_sched_barrier(0);
    bf16x8 af[2], bfr[2];
#pragma unroll
    for (int a = 0; a < 2; ++a)
      af[a] = *(const bf16x8*)(L[cur] + aO + a * 1024);
#pragma unroll
    for (int b = 0; b < 2; ++b)
      bfr[b] = *(const bf16x8*)(L[cur] + bO + b * 1024);
#pragma unroll
    for (int a = 0; a < 2; ++a)
#pragma unroll
      for (int b = 0; b < 2; ++b)
        acc[a][b] = __builtin_amdgcn_mfma_f32_16x16x32_bf16(af[a], bfr[b],
                                                            acc[a][b], 0, 0, 0);
  }
#undef ST1_STAGE

#pragma unroll
  for (int a = 0; a < 2; ++a)
#pragma unroll
    for (int b = 0; b < 2; ++b) {
      int col = n0 + wn * 32 + b * 16 + lr;
      float bv = bias1[col] + (bias2 ? bias2[col] : 0.0f);
#pragma unroll
      for (int j = 0; j < 4; ++j) {
        int rg = r0 + wm * 32 + a * 16 + kg * 4 + j;
        if (rg < M) out[(size_t)rg * 640 + col] = tanhf(acc[a][b][j] + bv);
      }
    }
}

// ---------------------------------------------------------------------------
// Materialize i8 joint A: A8[80128][656-pad] = q127(tanh(ta(+)tb)).
// ---------------------------------------------------------------------------
__global__ __launch_bounds__(256) void materialize8_kernel(
    const float* __restrict__ ta,   // [1600][640]
    const float* __restrict__ tb,   // [400][640]
    signed char* __restrict__ A8) { // [80128][656]
  const int idx = blockIdx.x * 256 + threadIdx.x;  // exactly 80000*80
  const int row = idx / 80;
  const int c8 = idx - row * 80;
  const int frow = row / 50;
  const int bidx = row / 10000;
  const int u = row - frow * 50;
  const float* tap = ta + (size_t)frow * 640 + c8 * 8;
  const float* tbp = tb + (size_t)(bidx * 50 + u) * 640 + c8 * 8;
  f32x4 xa0 = *(const f32x4*)tap, xa1 = *(const f32x4*)(tap + 4);
  f32x4 xb0 = *(const f32x4*)tbp, xb1 = *(const f32x4*)(tbp + 4);
  int q[8];
#pragma unroll
  for (int e = 0; e < 4; ++e) {
    float d0 = fmaxf(1.0f + xa0[e] * xb0[e], 1e-6f);
    q[e] = __float2int_rn((xa0[e] + xb0[e]) * __builtin_amdgcn_rcpf(d0) * 127.0f);
    float d1 = fmaxf(1.0f + xa1[e] * xb1[e], 1e-6f);
    q[e + 4] =
        __float2int_rn((xa1[e] + xb1[e]) * __builtin_amdgcn_rcpf(d1) * 127.0f);
  }
  i32x2 pk;
  pk[0] = (q[0] & 255) | ((q[1] & 255) << 8) | ((q[2] & 255) << 16) | (q[3] << 24);
  pk[1] = (q[4] & 255) | ((q[5] & 255) << 8) | ((q[6] & 255) << 16) | (q[7] << 24);
  *(i32x2*)(A8 + (size_t)row * 656 + c8 * 8) = pk;
}

// ---------------------------------------------------------------------------
// Stage 2 (R15 geometry, reverted): M-streaming joint GEMM, B in registers,
// continuous per-chunk stores. Block = (col-strip of 128, M-range of 256
// rows = 8 chunks of 32), grid 2560 (2504 active).
//  XCD map: mg=(orig&7)+8*(orig>>6), strip=(orig>>3)&7 -> 8 strips of one
//  mg adjacent on one XCD (A8 read from HBM ~once, L2-shared).
// ---------------------------------------------------------------------------
__global__ __launch_bounds__(512, 4) void joint_gemm_kernel(
    const signed char* __restrict__ A8,  // [80128][656]
    const signed char* __restrict__ W8,  // [1024][640]
    const float* __restrict__ b_out,     // [1024]
    float* __restrict__ out) {           // [80000][1024]
  __shared__ __align__(16) signed char Al[2][21504];  // chunk dbuf
  __shared__ __align__(16) float Tr[8][32 * 20];      // per-wave transpose
  const int tid = threadIdx.x;
  const int w = tid >> 6, l = tid & 63;
  const int lr = l & 15, kg = l >> 4;

  const int orig = blockIdx.x;  // grid 2560
  const int mg = (orig & 7) + 8 * (orig >> 6);
  const int strip = (orig >> 3) & 7;
  if (mg >= 313) return;
  const int c0w = strip * 128 + w * 16;

  // ---- B: 10 frags in registers, loaded once ----
  i32x4 Bf[10];
  const signed char* gW = W8 + (size_t)(c0w + lr) * 640 + kg * 16;
#pragma unroll
  for (int t = 0; t < 10; ++t) Bf[t] = *(const i32x4*)(gW + t * 64);
  const float bv = b_out[c0w + lr];

  // ---- staging assignment: wave w issues insts [w*3, min(w*3+3,21)) ----
  const int i0 = w * 3;
  const int ni = (i0 < 21) ? ((i0 + 3 <= 21) ? 3 : 21 - i0) : 0;
  const size_t mbase = (size_t)mg * 256 * 656;

#define JSTAGE(c, buf)                                                         \
  {                                                                            \
    const signed char* s_ = A8 + mbase + (size_t)(c) * (32 * 656);             \
    for (int k_ = 0; k_ < ni; ++k_) {                                          \
      const int i_ = i0 + k_;                                                  \
      const int off_ = (i_ == 20) ? 19968 : i_ * 1024;                         \
      GLOAD_LDS16(s_ + off_ + l * 16, Al[buf] + off_);                         \
    }                                                                          \
  }

  // ---- prologue: stage chunk 0 ----
  JSTAGE(0, 0);

  const float cfac = SW_SCALE / (127.0f * 127.0f);
  float* trw = Tr[w];

#pragma unroll 1
  for (int c = 0; c < 8; ++c) {
    const int buf = c & 1;
    if (c < 7) JSTAGE(c + 1, buf ^ 1);
    __builtin_amdgcn_sched_barrier(0);
    // FIFO ledger: queue = [gloads(c)=3][stores(c-1)=2][gloads(c+1)=3]
    if (c == 0) {
      asm volatile("s_waitcnt vmcnt(3)" ::: "memory");  // B + bv + g0 done
    } else if (c < 7) {
      asm volatile("s_waitcnt vmcnt(5)" ::: "memory");  // g(c) done
    } else {
      asm volatile("s_waitcnt vmcnt(2)" ::: "memory");  // g7 done
    }
    __builtin_amdgcn_sched_barrier(0);
    __builtin_amdgcn_s_barrier();  // all waves' parts of chunk c visible
    __builtin_amdgcn_sched_barrier(0);

    // ---- compute: 2 row-groups x 10 K-frags ----
    i32x4 acc0 = {}, acc1 = {};
#pragma unroll
    for (int t = 0; t < 10; ++t) {
      i32x4 a0 = *(const i32x4*)(Al[buf] + lr * 656 + t * 64 + kg * 16);
      i32x4 a1 = *(const i32x4*)(Al[buf] + (16 + lr) * 656 + t * 64 + kg * 16);
      acc0 = __builtin_amdgcn_mfma_i32_16x16x64_i8(a0, Bf[t], acc0, 0, 0, 0);
      acc1 = __builtin_amdgcn_mfma_i32_16x16x64_i8(a1, Bf[t], acc1, 0, 0, 0);
    }

    // ---- per-wave transpose (Tr private -> no cross-wave sync) ----
#pragma unroll
    for (int j = 0; j < 4; ++j) {
      trw[(kg * 4 + j) * 20 + lr] = (float)acc0[j] * cfac + bv;
      trw[(16 + kg * 4 + j) * 20 + lr] = (float)acc1[j] * cfac + bv;
    }
    asm volatile("s_waitcnt lgkmcnt(0)" ::: "memory");
    // ---- stores: 2 x nt dwordx4 per lane ----
    const int part = l & 3;
#pragma unroll
    for (int it = 0; it < 2; ++it) {
      const int row = it * 16 + (l >> 2);
      f32x4 v = *(const f32x4*)(trw + row * 20 + part * 4);
      const int grow = mg * 256 + c * 32 + row;
      if (grow < 80000)
        __builtin_nontemporal_store(
            v, (f32x4*)(out + (size_t)grow * 1024 + c0w + part * 4));
    }
    __builtin_amdgcn_sched_barrier(0);
    __builtin_amdgcn_s_barrier();  // reads of chunk c done before reuse
  }
#undef JSTAGE
}

// ---------------------------------------------------------------------------
extern "C" void kernel_launch(void* const* d_in, const int* in_sizes, int n_in,
                              void* d_out, int out_size, void* d_ws,
                              size_t ws_size, hipStream_t stream) {
  const float* enc = (const float*)d_in[0];
  const float* dec = (const float*)d_in[1];
  const float* ot = (const float*)d_in[2];
  const float* W_enc = (const float*)d_in[3];
  const float* b_enc = (const float*)d_in[4];
  const float* W_ot = (const float*)d_in[5];
  const float* b_ot = (const float*)d_in[6];
  const float* W_dec = (const float*)d_in[7];
  const float* b_dec = (const float*)d_in[8];
  const float* W_out = (const float*)d_in[9];
  const float* b_out = (const float*)d_in[10];
  float* out = (float*)d_out;

  char* ws = (char*)d_ws;
  size_t off = 0;
  auto alloc = [&](size_t bytes) {
    void* p = ws + off;
    off += (bytes + 255) & ~(size_t)255;
    return p;
  };
  float* ta = (float*)alloc(1600 * 640 * 4);
  float* tb = (float*)alloc(400 * 640 * 4);
  bf16_t* Acat = (bf16_t*)alloc(1600 * 1024 * 2);
  bf16_t* Dec = (bf16_t*)alloc(400 * 512 * 2);
  bf16_t* WcatT = (bf16_t*)alloc(640 * 1024 * 2);
  bf16_t* WdecT = (bf16_t*)alloc(640 * 512 * 2);
  signed char* WoutT8 = (signed char*)alloc(1024 * 640);
  signed char* A8 = (signed char*)alloc((size_t)80128 * 656);

  prep_kernel<<<2500, 256, 0, stream>>>(enc, dec, ot, W_enc, W_ot, W_dec,
                                        W_out, Acat, Dec, WcatT, WdecT, WoutT8);
  // merged stage 1: y<25 -> ta (M=1600,K=1024); y>=25 -> tb (M=400,K=512)
  stage1_kernel<<<dim3(10, 32), 256, 0, stream>>>(Acat, WcatT, b_enc, b_ot, ta,
                                                  Dec, WdecT, b_dec, tb);
  materialize8_kernel<<<25000, 256, 0, stream>>>(ta, tb, A8);
  // joint: M-streaming, 256-row ranges (8 chunks), continuous stores
  joint_gemm_kernel<<<2560, 512, 0, stream>>>(A8, WoutT8, b_out, out);
}

// Round 18
// 132.276 us; speedup vs baseline: 1.1170x; 1.0447x over previous
//
#include <hip/hip_runtime.h>
#include <math.h>

typedef __bf16 bf16_t;
typedef __bf16 bf16x8 __attribute__((ext_vector_type(8)));
typedef float f32x4 __attribute__((ext_vector_type(4)));
typedef int i32x4 __attribute__((ext_vector_type(4)));
typedef int i32x2 __attribute__((ext_vector_type(2)));

#define SW_SCALE 0.03952847075f /* 1/sqrt(640) */

#define GLOAD_LDS16(g, l)                                                      \
  __builtin_amdgcn_global_load_lds(                                            \
      (const __attribute__((address_space(1))) void*)(g),                      \
      (__attribute__((address_space(3))) void*)(l), 16, 0, 0)

// ---------------------------------------------------------------------------
// Prep: bf16 stage-1 operands + plain i8 [v][f] W_out.
// ---------------------------------------------------------------------------
__global__ __launch_bounds__(256) void prep_kernel(
    const float* __restrict__ enc, const float* __restrict__ dec,
    const float* __restrict__ ot, const float* __restrict__ W_enc,
    const float* __restrict__ W_ot, const float* __restrict__ W_dec,
    const float* __restrict__ W_out, bf16_t* __restrict__ Acat,
    bf16_t* __restrict__ Dec, bf16_t* __restrict__ WcatT,
    bf16_t* __restrict__ WdecT, signed char* __restrict__ WoutT8) {
  __shared__ float T[32][33];
  const int tid = threadIdx.x;
  const int b = blockIdx.x;

  if (b < 900) {  // elementwise bf16x8 copies
    const int idx8 = (b * 256 + tid) * 8;
    const int N0 = 1600 * 1024;
    if (idx8 < N0) {
      const int r = idx8 >> 10, c = idx8 & 1023;
      const float* src = (c < 512) ? enc + (r << 9) + c : ot + (r << 9) + c - 512;
      f32x4 v0 = *(const f32x4*)src;
      f32x4 v1 = *(const f32x4*)(src + 4);
      bf16x8 o;
#pragma unroll
      for (int e = 0; e < 4; ++e) {
        o[e] = (bf16_t)v0[e];
        o[e + 4] = (bf16_t)v1[e];
      }
      *(bf16x8*)(Acat + idx8) = o;
    } else {
      const int j = idx8 - N0;
      if (j < 400 * 512) {
        f32x4 v0 = *(const f32x4*)(dec + j);
        f32x4 v1 = *(const f32x4*)(dec + j + 4);
        bf16x8 o;
#pragma unroll
        for (int e = 0; e < 4; ++e) {
          o[e] = (bf16_t)v0[e];
          o[e + 4] = (bf16_t)v1[e];
        }
        *(bf16x8*)(Dec + j) = o;
      }
    }
    return;
  }

  const int tx = tid & 31, ty = tid >> 5;
  if (b < 1540) {  // WcatT [f][k] <- [k][f]
    const int b2 = b - 900;
    const int kt = b2 / 20, ft = b2 - kt * 20;
    const int k0 = kt * 32, f0 = ft * 32;
#pragma unroll
    for (int j = 0; j < 4; ++j) {
      const int kk = k0 + ty + j * 8;
      T[ty + j * 8][tx] = (kk < 512) ? W_enc[kk * 640 + f0 + tx]
                                     : W_ot[(kk - 512) * 640 + f0 + tx];
    }
    __syncthreads();
#pragma unroll
    for (int j = 0; j < 4; ++j) {
      const int ff = f0 + ty + j * 8;
      WcatT[ff * 1024 + k0 + tx] = (bf16_t)T[tx][ty + j * 8];
    }
    return;
  }
  if (b < 1860) {  // WdecT [f][k] <- [k][f]
    const int b2 = b - 1540;
    const int kt = b2 / 20, ft = b2 - kt * 20;
    const int k0 = kt * 32, f0 = ft * 32;
#pragma unroll
    for (int j = 0; j < 4; ++j)
      T[ty + j * 8][tx] = W_dec[(k0 + ty + j * 8) * 640 + f0 + tx];
    __syncthreads();
#pragma unroll
    for (int j = 0; j < 4; ++j) {
      const int ff = f0 + ty + j * 8;
      WdecT[ff * 512 + k0 + tx] = (bf16_t)T[tx][ty + j * 8];
    }
    return;
  }
  {  // WoutT8 [v][f] i8 <- W_out [f][v], 32x32 tiles
    const int b2 = b - 1860;  // 0..639
    const int vt = b2 / 20, ft = b2 - vt * 20;
    const int v0 = vt * 32, f0 = ft * 32;
#pragma unroll
    for (int j = 0; j < 4; ++j)
      T[ty + j * 8][tx] = W_out[(f0 + ty + j * 8) * 1024 + v0 + tx];
    __syncthreads();
#pragma unroll
    for (int j = 0; j < 4; ++j) {
      const int vv = v0 + ty + j * 8;
      float w = T[tx][ty + j * 8] * (127.0f / SW_SCALE);
      w = fminf(fmaxf(w, -127.0f), 127.0f);
      WoutT8[(size_t)vv * 640 + f0 + tx] = (signed char)__float2int_rn(w);
    }
  }
}

// ---------------------------------------------------------------------------
// Stage 1 (merged, dist-2): both tanh-GEMMs in one dispatch; barrier-free,
// wave-private LDS, 3-slot ring, vmcnt(8) ledger.
// ---------------------------------------------------------------------------
__global__ __launch_bounds__(256) void stage1_kernel(
    const bf16_t* __restrict__ Acat, const bf16_t* __restrict__ WcatT,
    const float* __restrict__ b_enc, const float* __restrict__ b_ot,
    float* __restrict__ ta, const bf16_t* __restrict__ Dec,
    const bf16_t* __restrict__ WdecT, const float* __restrict__ b_dec,
    float* __restrict__ tb) {
  __shared__ __align__(16) unsigned char L[3][16384];
  const int tid = threadIdx.x;
  const int wid = tid >> 6, l = tid & 63;
  const int wm = wid >> 1, wn = wid & 1;

  const bool big = (blockIdx.y < 25);
  const int M = big ? 1600 : 400;
  const int K = big ? 1024 : 512;
  const bf16_t* A = big ? Acat : Dec;
  const bf16_t* Bt = big ? WcatT : WdecT;
  const float* bias1 = big ? b_enc : b_dec;
  const float* bias2 = big ? b_ot : nullptr;
  float* out = big ? ta : tb;
  const int r0 = (big ? blockIdx.y : blockIdx.y - 25) * 64;
  const int n0 = blockIdx.x * 64;

  const int sperm = ((l & 3) ^ ((l >> 3) & 3)) * 8;
  int ra0 = r0 + wm * 32 + (l >> 2);
  if (ra0 > M - 1) ra0 = M - 1;
  int ra1 = r0 + wm * 32 + 16 + (l >> 2);
  if (ra1 > M - 1) ra1 = M - 1;
  const bf16_t* gA0 = A + (size_t)ra0 * K + sperm;
  const bf16_t* gA1 = A + (size_t)ra1 * K + sperm;
  const bf16_t* gB0 = Bt + (size_t)(n0 + wn * 32 + (l >> 2)) * K + sperm;
  const bf16_t* gB1 = gB0 + (size_t)16 * K;
  const int wb = wid * 4096;

  const int lr = l & 15, kg = l >> 4;
  const int swz = (kg ^ ((lr >> 1) & 3)) << 4;
  const int aO = wb + lr * 64 + swz;
  const int bO = wb + 2048 + lr * 64 + swz;

#define ST1_STAGE(t, s)                                                        \
  {                                                                            \
    GLOAD_LDS16(gA0 + (t) * 32, L[s] + wb);                                    \
    GLOAD_LDS16(gA1 + (t) * 32, L[s] + wb + 1024);                             \
    GLOAD_LDS16(gB0 + (t) * 32, L[s] + wb + 2048);                             \
    GLOAD_LDS16(gB1 + (t) * 32, L[s] + wb + 3072);                             \
  }

  f32x4 acc[2][2] = {};
  const int steps = K >> 5;  // 32 or 16
  ST1_STAGE(0, 0);
  ST1_STAGE(1, 1);
#pragma unroll 1
  for (int ks = 0; ks < steps; ++ks) {
    const int cur = ks % 3;
    if (ks < steps - 2) {
      ST1_STAGE(ks + 2, (ks + 2) % 3);
      __builtin_amdgcn_sched_barrier(0);
      asm volatile("s_waitcnt vmcnt(8)" ::: "memory");  // g(ks) landed
    } else if (ks == steps - 2) {
      asm volatile("s_waitcnt vmcnt(4)" ::: "memory");
    } else {
      asm volatile("s_waitcnt vmcnt(0)" ::: "memory");
    }
    __builtin_amdgcn_sched_barrier(0);
    bf16x8 af[2], bfr[2];
#pragma unroll
    for (int a = 0; a < 2; ++a)
      af[a] = *(const bf16x8*)(L[cur] + aO + a * 1024);
#pragma unroll
    for (int b = 0; b < 2; ++b)
      bfr[b] = *(const bf16x8*)(L[cur] + bO + b * 1024);
#pragma unroll
    for (int a = 0; a < 2; ++a)
#pragma unroll
      for (int b = 0; b < 2; ++b)
        acc[a][b] = __builtin_amdgcn_mfma_f32_16x16x32_bf16(af[a], bfr[b],
                                                            acc[a][b], 0, 0, 0);
  }
#undef ST1_STAGE

#pragma unroll
  for (int a = 0; a < 2; ++a)
#pragma unroll
    for (int b = 0; b < 2; ++b) {
      int col = n0 + wn * 32 + b * 16 + lr;
      float bv = bias1[col] + (bias2 ? bias2[col] : 0.0f);
#pragma unroll
      for (int j = 0; j < 4; ++j) {
        int rg = r0 + wm * 32 + a * 16 + kg * 4 + j;
        if (rg < M) out[(size_t)rg * 640 + col] = tanhf(acc[a][b][j] + bv);
      }
    }
}

// ---------------------------------------------------------------------------
// Materialize i8 joint A: A8[80128][656-pad] = q127(tanh(ta(+)tb)).
// ---------------------------------------------------------------------------
__global__ __launch_bounds__(256) void materialize8_kernel(
    const float* __restrict__ ta,   // [1600][640]
    const float* __restrict__ tb,   // [400][640]
    signed char* __restrict__ A8) { // [80128][656]
  const int idx = blockIdx.x * 256 + threadIdx.x;  // exactly 80000*80
  const int row = idx / 80;
  const int c8 = idx - row * 80;
  const int frow = row / 50;
  const int bidx = row / 10000;
  const int u = row - frow * 50;
  const float* tap = ta + (size_t)frow * 640 + c8 * 8;
  const float* tbp = tb + (size_t)(bidx * 50 + u) * 640 + c8 * 8;
  f32x4 xa0 = *(const f32x4*)tap, xa1 = *(const f32x4*)(tap + 4);
  f32x4 xb0 = *(const f32x4*)tbp, xb1 = *(const f32x4*)(tbp + 4);
  int q[8];
#pragma unroll
  for (int e = 0; e < 4; ++e) {
    float d0 = fmaxf(1.0f + xa0[e] * xb0[e], 1e-6f);
    q[e] = __float2int_rn((xa0[e] + xb0[e]) * __builtin_amdgcn_rcpf(d0) * 127.0f);
    float d1 = fmaxf(1.0f + xa1[e] * xb1[e], 1e-6f);
    q[e + 4] =
        __float2int_rn((xa1[e] + xb1[e]) * __builtin_amdgcn_rcpf(d1) * 127.0f);
  }
  i32x2 pk;
  pk[0] = (q[0] & 255) | ((q[1] & 255) << 8) | ((q[2] & 255) << 16) | (q[3] << 24);
  pk[1] = (q[4] & 255) | ((q[5] & 255) << 8) | ((q[6] & 255) << 16) | (q[7] << 24);
  *(i32x2*)(A8 + (size_t)row * 656 + c8 * 8) = pk;
}

// ---------------------------------------------------------------------------
// Stage 2 (R18): R15/R17 M-streaming joint GEMM at 3 BLOCKS/CU.
//  Identical geometry/schedule to R17 (2560 blocks, 256-row M-ranges,
//  8 chunks of 32 rows, B-in-regs, continuous per-chunk nt stores).
//  Occupancy change only: Tr halved to 16-row strips (20->10 KB; epilogue
//  per chunk = two write16->lgkm->read->store passes, wave-private) gives
//  LDS 52 KB -> 3 blocks/CU; launch_bounds(512,6) caps VGPR ~85 so 24
//  waves/CU are schedulable. Extends R15's proven cross-block store-drain
//  overlap mechanism from 2 to 3 co-resident blocks.
// ---------------------------------------------------------------------------
__global__ __launch_bounds__(512, 6) void joint_gemm_kernel(
    const signed char* __restrict__ A8,  // [80128][656]
    const signed char* __restrict__ W8,  // [1024][640]
    const float* __restrict__ b_out,     // [1024]
    float* __restrict__ out) {           // [80000][1024]
  __shared__ __align__(16) signed char Al[2][21504];  // chunk dbuf (42 KB)
  __shared__ __align__(16) float Tr[8][16 * 20];      // 16-row strips (10 KB)
  const int tid = threadIdx.x;
  const int w = tid >> 6, l = tid & 63;
  const int lr = l & 15, kg = l >> 4;

  const int orig = blockIdx.x;  // grid 2560
  const int mg = (orig & 7) + 8 * (orig >> 6);
  const int strip = (orig >> 3) & 7;
  if (mg >= 313) return;
  const int c0w = strip * 128 + w * 16;

  // ---- B: 10 frags in registers, loaded once ----
  i32x4 Bf[10];
  const signed char* gW = W8 + (size_t)(c0w + lr) * 640 + kg * 16;
#pragma unroll
  for (int t = 0; t < 10; ++t) Bf[t] = *(const i32x4*)(gW + t * 64);
  const float bv = b_out[c0w + lr];

  // ---- staging assignment: wave w issues insts [w*3, min(w*3+3,21)) ----
  const int i0 = w * 3;
  const int ni = (i0 < 21) ? ((i0 + 3 <= 21) ? 3 : 21 - i0) : 0;
  const size_t mbase = (size_t)mg * 256 * 656;

#define JSTAGE(c, buf)                                                         \
  {                                                                            \
    const signed char* s_ = A8 + mbase + (size_t)(c) * (32 * 656);             \
    for (int k_ = 0; k_ < ni; ++k_) {                                          \
      const int i_ = i0 + k_;                                                  \
      const int off_ = (i_ == 20) ? 19968 : i_ * 1024;                         \
      GLOAD_LDS16(s_ + off_ + l * 16, Al[buf] + off_);                         \
    }                                                                          \
  }

  // ---- prologue: stage chunk 0 ----
  JSTAGE(0, 0);

  const float cfac = SW_SCALE / (127.0f * 127.0f);
  float* trw = Tr[w];
  const int part = l & 3;
  const int srow = l >> 2;  // store row within 16-row strip

#pragma unroll 1
  for (int c = 0; c < 8; ++c) {
    const int buf = c & 1;
    if (c < 7) JSTAGE(c + 1, buf ^ 1);
    __builtin_amdgcn_sched_barrier(0);
    // FIFO ledger: queue = [gloads(c)=3][stores(c-1)=4][gloads(c+1)=3]
    if (c == 0) {
      asm volatile("s_waitcnt vmcnt(3)" ::: "memory");  // B + bv + g0 done
    } else if (c < 7) {
      asm volatile("s_waitcnt vmcnt(7)" ::: "memory");  // g(c) done
    } else {
      asm volatile("s_waitcnt vmcnt(4)" ::: "memory");  // g7 done
    }
    __builtin_amdgcn_sched_barrier(0);
    __builtin_amdgcn_s_barrier();  // all waves' parts of chunk c visible
    __builtin_amdgcn_sched_barrier(0);

    // ---- compute: 2 row-groups x 10 K-frags ----
    i32x4 acc0 = {}, acc1 = {};
#pragma unroll
    for (int t = 0; t < 10; ++t) {
      i32x4 a0 = *(const i32x4*)(Al[buf] + lr * 656 + t * 64 + kg * 16);
      i32x4 a1 = *(const i32x4*)(Al[buf] + (16 + lr) * 656 + t * 64 + kg * 16);
      acc0 = __builtin_amdgcn_mfma_i32_16x16x64_i8(a0, Bf[t], acc0, 0, 0, 0);
      acc1 = __builtin_amdgcn_mfma_i32_16x16x64_i8(a1, Bf[t], acc1, 0, 0, 0);
    }

    // ---- epilogue: two 16-row passes (wave-private strip; no barriers) ----
#pragma unroll
    for (int j = 0; j < 4; ++j)
      trw[(kg * 4 + j) * 20 + lr] = (float)acc0[j] * cfac + bv;
    asm volatile("s_waitcnt lgkmcnt(0)" ::: "memory");
    {
      f32x4 v = *(const f32x4*)(trw + srow * 20 + part * 4);
      asm volatile("s_waitcnt lgkmcnt(0)" ::: "memory");
      const int grow = mg * 256 + c * 32 + srow;
      if (grow < 80000)
        __builtin_nontemporal_store(
            v, (f32x4*)(out + (size_t)grow * 1024 + c0w + part * 4));
    }
#pragma unroll
    for (int j = 0; j < 4; ++j)
      trw[(kg * 4 + j) * 20 + lr] = (float)acc1[j] * cfac + bv;
    asm volatile("s_waitcnt lgkmcnt(0)" ::: "memory");
    {
      f32x4 v = *(const f32x4*)(trw + srow * 20 + part * 4);
      asm volatile("s_waitcnt lgkmcnt(0)" ::: "memory");
      const int grow = mg * 256 + c * 32 + 16 + srow;
      if (grow < 80000)
        __builtin_nontemporal_store(
            v, (f32x4*)(out + (size_t)grow * 1024 + c0w + part * 4));
    }
    __builtin_amdgcn_sched_barrier(0);
    __builtin_amdgcn_s_barrier();  // reads of chunk c done before reuse
  }
#undef JSTAGE
}

// ---------------------------------------------------------------------------
extern "C" void kernel_launch(void* const* d_in, const int* in_sizes, int n_in,
                              void* d_out, int out_size, void* d_ws,
                              size_t ws_size, hipStream_t stream) {
  const float* enc = (const float*)d_in[0];
  const float* dec = (const float*)d_in[1];
  const float* ot = (const float*)d_in[2];
  const float* W_enc = (const float*)d_in[3];
  const float* b_enc = (const float*)d_in[4];
  const float* W_ot = (const float*)d_in[5];
  const float* b_ot = (const float*)d_in[6];
  const float* W_dec = (const float*)d_in[7];
  const float* b_dec = (const float*)d_in[8];
  const float* W_out = (const float*)d_in[9];
  const float* b_out = (const float*)d_in[10];
  float* out = (float*)d_out;

  char* ws = (char*)d_ws;
  size_t off = 0;
  auto alloc = [&](size_t bytes) {
    void* p = ws + off;
    off += (bytes + 255) & ~(size_t)255;
    return p;
  };
  float* ta = (float*)alloc(1600 * 640 * 4);
  float* tb = (float*)alloc(400 * 640 * 4);
  bf16_t* Acat = (bf16_t*)alloc(1600 * 1024 * 2);
  bf16_t* Dec = (bf16_t*)alloc(400 * 512 * 2);
  bf16_t* WcatT = (bf16_t*)alloc(640 * 1024 * 2);
  bf16_t* WdecT = (bf16_t*)alloc(640 * 512 * 2);
  signed char* WoutT8 = (signed char*)alloc(1024 * 640);
  signed char* A8 = (signed char*)alloc((size_t)80128 * 656);

  prep_kernel<<<2500, 256, 0, stream>>>(enc, dec, ot, W_enc, W_ot, W_dec,
                                        W_out, Acat, Dec, WcatT, WdecT, WoutT8);
  // merged stage 1: y<25 -> ta (M=1600,K=1024); y>=25 -> tb (M=400,K=512)
  stage1_kernel<<<dim3(10, 32), 256, 0, stream>>>(Acat, WcatT, b_enc, b_ot, ta,
                                                  Dec, WdecT, b_dec, tb);
  materialize8_kernel<<<25000, 256, 0, stream>>>(ta, tb, A8);
  // joint: M-streaming, 256-row ranges, continuous stores, 3 blocks/CU
  joint_gemm_kernel<<<2560, 512, 0, stream>>>(A8, WoutT8, b_out, out);
}